// Round 1
// baseline (370.729 us; speedup 1.0000x reference)
//
#include <hip/hip_runtime.h>

// Problem constants: B=32, T=4096, C=256, WINDOW=8, HEADS=4, hd=64
// Rows M = B*T = 131072. qkv col n = part*256 + h*64 + d.

typedef __attribute__((ext_vector_type(8))) short short8;
typedef __attribute__((ext_vector_type(4))) short short4v;
typedef __attribute__((ext_vector_type(4))) float float4v;

// Packed fp32x2 -> bf16x2 (RNE) in one instruction.
__device__ inline unsigned cvtpk_bf16(float a, float b) {
  unsigned r;
  asm("v_cvt_pk_bf16_f32 %0, %1, %2" : "=v"(r) : "v"(a), "v"(b));
  return r;
}

// ---- prologue: cast weights fp32 -> bf16 into workspace ----
// dst layout: [768*256] w_qkv_bf16, then [256*256] w_proj_bf16
__global__ void __launch_bounds__(256) wconv_kernel(const float* __restrict__ wqkv,
                                                    const float* __restrict__ wproj,
                                                    short* __restrict__ dst) {
  int i = blockIdx.x * 256 + threadIdx.x;          // 65536 threads, 4 elems each
  float4 v;
  if (i < 49152) v = reinterpret_cast<const float4*>(wqkv)[i];
  else           v = reinterpret_cast<const float4*>(wproj)[i - 49152];
  reinterpret_cast<uint2*>(dst)[i] =
      make_uint2(cvtpk_bf16(v.x, v.y), cvtpk_bf16(v.z, v.w));
}

// ---- fused QKV + windowed attention + proj ----
__global__ void __launch_bounds__(256, 2) attn_kernel(
    const float* __restrict__ x,
    const short* __restrict__ wbf,      // bf16 weights from workspace
    const float* __restrict__ b_qkv,
    const float* __restrict__ b_proj,
    float* __restrict__ out) {

  // LDS: 64512 B total -> 2 blocks/CU
  __shared__ short sA[64 * 264];        // X tile bf16 (row-major, stride 264); later aliased as attn-out tile
  __shared__ short sQK[2 * 64 * 72];    // per-head Q,K rows [token][d], stride 72
  __shared__ short sVT[64 * 72];        // per-head V^T [d][token], stride 72
  __shared__ short sP[4 * 16 * 24];     // per-wave P tile [q][k], stride 24

  const int tid  = threadIdx.x;
  const int wv   = tid >> 6;            // wave 0..3
  const int lane = tid & 63;
  const int L    = lane & 15;
  const int quad = lane >> 4;           // 0..3
  const int bid  = blockIdx.x;
  // softmax window-select: lane's q-window ((lane>>3)&1) vs which half holds it (lane>>5)
  const bool selw = (((lane >> 5) ^ (lane >> 3)) & 1);

  const float4v fzero = {0.f, 0.f, 0.f, 0.f};

  // ---------- Phase 0: stage X tile (64x256 fp32 -> bf16 LDS) ----------
  const float* xg = x + (size_t)bid * (64 * 256);
  #pragma unroll
  for (int i = 0; i < 16; ++i) {
    int idx = i * 1024 + tid * 4;
    float4 v = *reinterpret_cast<const float4*>(xg + idx);
    int row = idx >> 8;
    int col = idx & 255;
    *reinterpret_cast<uint2*>(&sA[row * 264 + col]) =
        make_uint2(cvtpk_bf16(v.x, v.y), cvtpk_bf16(v.z, v.w));
  }
  __syncthreads();

  float oreg[4][16];                    // attention output per head: [dchunk*4 + reg]

  #pragma unroll
  for (int h = 0; h < 4; ++h) {
    // ---------- QKV GEMM: this wave computes cols [wv*48, wv*48+48) of head-local 192 ----------
    float4v acc[4][3];
    #pragma unroll
    for (int rt = 0; rt < 4; ++rt)
      #pragma unroll
      for (int ct = 0; ct < 3; ++ct) acc[rt][ct] = fzero;

    const short* wb[3];
    int s_[3], d0_[3];
    #pragma unroll
    for (int ct = 0; ct < 3; ++ct) {
      int c0 = wv * 48 + ct * 16;       // head-local col
      int s  = c0 >> 6;                 // 0=q 1=k 2=v
      int d0 = c0 & 63;
      s_[ct] = s; d0_[ct] = d0;
      int wrow0 = s * 256 + h * 64 + d0;                 // row in w_qkv
      wb[ct] = wbf + (size_t)(wrow0 + L) * 256 + quad * 8;
    }

    #pragma unroll
    for (int kk = 0; kk < 8; ++kk) {
      short8 a[4];
      #pragma unroll
      for (int rt = 0; rt < 4; ++rt)
        a[rt] = *reinterpret_cast<const short8*>(&sA[(rt * 16 + L) * 264 + kk * 32 + quad * 8]);
      short8 b[3];
      #pragma unroll
      for (int ct = 0; ct < 3; ++ct)
        b[ct] = *reinterpret_cast<const short8*>(wb[ct] + kk * 32);
      #pragma unroll
      for (int rt = 0; rt < 4; ++rt)
        #pragma unroll
        for (int ct = 0; ct < 3; ++ct)
          acc[rt][ct] = __builtin_amdgcn_mfma_f32_16x16x32_bf16(a[rt], b[ct], acc[rt][ct], 0, 0, 0);
    }

    // epilogue: + bias, scatter to sQK (row-major) / sVT (transposed), packed cvt
    #pragma unroll
    for (int ct = 0; ct < 3; ++ct) {
      int s = s_[ct], d0 = d0_[ct];
      float bias = b_qkv[s * 256 + h * 64 + d0 + L];
      #pragma unroll
      for (int rt = 0; rt < 4; ++rt) {
        float4v v = acc[rt][ct];
        unsigned u01 = cvtpk_bf16(v[0] + bias, v[1] + bias);
        unsigned u23 = cvtpk_bf16(v[2] + bias, v[3] + bias);
        if (s < 2) {
          short* dq = &sQK[s * (64 * 72) + (rt * 16 + quad * 4) * 72 + d0 + L];
          dq[0]   = (short)u01;
          dq[72]  = (short)(u01 >> 16);
          dq[144] = (short)u23;
          dq[216] = (short)(u23 >> 16);
        } else {
          *reinterpret_cast<uint2*>(&sVT[(d0 + L) * 72 + rt * 16 + quad * 4]) =
              make_uint2(u01, u23);
        }
      }
    }
    __syncthreads();

    // ---------- attention: wave owns tokens [wv*16, wv*16+16) = 2 windows ----------
    // Swapped operands: mfma(K, Q) -> S^T: row i = local k = quad*4+r, col j = local q = L.
    // Each lane holds one q's scores for 4 k's -> k-reduction is in-register + 2 shuffles.
    float4v sacc = fzero;
    #pragma unroll
    for (int ks = 0; ks < 2; ++ks) {
      short8 qa = *reinterpret_cast<const short8*>(&sQK[(wv * 16 + L) * 72 + ks * 32 + quad * 8]);
      short8 kb = *reinterpret_cast<const short8*>(&sQK[64 * 72 + (wv * 16 + L) * 72 + ks * 32 + quad * 8]);
      sacc = __builtin_amdgcn_mfma_f32_16x16x32_bf16(kb, qa, sacc, 0, 0, 0);
    }

    // in-register softmax (q = L, k = quad*4+r)
    float sv[4];
    #pragma unroll
    for (int r = 0; r < 4; ++r) {
      int kidx = quad * 4 + r;
      bool valid = ((kidx >> 3) == (L >> 3)) && ((kidx & 7) <= (L & 7));  // same window + causal
      sv[r] = valid ? sacc[r] * 0.125f : -1e30f;
    }
    float mx = fmaxf(fmaxf(sv[0], sv[1]), fmaxf(sv[2], sv[3]));
    mx = fmaxf(mx, __shfl_xor(mx, 16));          // combine quad pairs: lanes<32 hold win A, >=32 win B
    {
      float mo = __shfl_xor(mx, 32);
      if (selw) mx = mo;                          // pick this lane's q-window
    }
    float e[4];
    float sum = 0.f;
    #pragma unroll
    for (int r = 0; r < 4; ++r) { e[r] = __expf(sv[r] - mx); sum += e[r]; }
    sum += __shfl_xor(sum, 16);
    {
      float so = __shfl_xor(sum, 32);
      if (selw) sum = so;
    }
    float rs = __builtin_amdgcn_rcpf(sum);
    short* sPw = &sP[wv * (16 * 24)];
    *reinterpret_cast<uint2*>(&sPw[L * 24 + quad * 4]) =
        make_uint2(cvtpk_bf16(e[0] * rs, e[1] * rs), cvtpk_bf16(e[2] * rs, e[3] * rs));

    // P @ V via 16x16x32 with K zero-padded 16->32 (A=0 for quads 2,3; B token clamped)
    short8 pa = {0, 0, 0, 0, 0, 0, 0, 0};
    if (quad < 2) pa = *reinterpret_cast<const short8*>(&sPw[L * 24 + quad * 8]);
    #pragma unroll
    for (int dc = 0; dc < 4; ++dc) {
      short8 vb = *reinterpret_cast<const short8*>(
          &sVT[(dc * 16 + L) * 72 + wv * 16 + (quad & 1) * 8]);
      float4v o = __builtin_amdgcn_mfma_f32_16x16x32_bf16(pa, vb, fzero, 0, 0, 0);
      #pragma unroll
      for (int r = 0; r < 4; ++r) oreg[h][dc * 4 + r] = o[r];
    }
    if (h != 3) __syncthreads();   // protect sQK/sVT before next head's epilogue writes
    // (h==3: no next epilogue; sA attn-out writes below only race vs. head-3 GEMM reads,
    //  which are already fenced by this head's post-epilogue barrier)
  }

  // ---------- write attention output tile into sA (X tile is dead) ----------
  #pragma unroll
  for (int h = 0; h < 4; ++h)
    #pragma unroll
    for (int dc = 0; dc < 4; ++dc) {
      unsigned u01 = cvtpk_bf16(oreg[h][dc * 4 + 0], oreg[h][dc * 4 + 1]);
      unsigned u23 = cvtpk_bf16(oreg[h][dc * 4 + 2], oreg[h][dc * 4 + 3]);
      short* dq = &sA[(wv * 16 + quad * 4) * 264 + h * 64 + dc * 16 + L];
      dq[0]       = (short)u01;
      dq[264]     = (short)(u01 >> 16);
      dq[528]     = (short)u23;
      dq[792]     = (short)(u23 >> 16);
    }
  __syncthreads();

  // ---------- proj GEMM: wave computes cols [wv*64, wv*64+64) ----------
  float4v pacc[4][4];
  #pragma unroll
  for (int rt = 0; rt < 4; ++rt)
    #pragma unroll
    for (int ct = 0; ct < 4; ++ct) pacc[rt][ct] = fzero;

  const short* wp = wbf + 768 * 256;
  const short* wpb[4];
  #pragma unroll
  for (int ct = 0; ct < 4; ++ct)
    wpb[ct] = wp + (size_t)(wv * 64 + ct * 16 + L) * 256 + quad * 8;

  #pragma unroll
  for (int kk = 0; kk < 8; ++kk) {
    short8 a[4];
    #pragma unroll
    for (int rt = 0; rt < 4; ++rt)
      a[rt] = *reinterpret_cast<const short8*>(&sA[(rt * 16 + L) * 264 + kk * 32 + quad * 8]);
    short8 b[4];
    #pragma unroll
    for (int ct = 0; ct < 4; ++ct)
      b[ct] = *reinterpret_cast<const short8*>(wpb[ct] + kk * 32);
    #pragma unroll
    for (int rt = 0; rt < 4; ++rt)
      #pragma unroll
      for (int ct = 0; ct < 4; ++ct)
        pacc[rt][ct] = __builtin_amdgcn_mfma_f32_16x16x32_bf16(a[rt], b[ct], pacc[rt][ct], 0, 0, 0);
  }

  // epilogue: + bias, fp32 store
  float* og = out + (size_t)bid * (64 * 256);
  #pragma unroll
  for (int ct = 0; ct < 4; ++ct) {
    float bias = b_proj[wv * 64 + ct * 16 + L];
    #pragma unroll
    for (int rt = 0; rt < 4; ++rt)
      #pragma unroll
      for (int r = 0; r < 4; ++r)
        og[(rt * 16 + quad * 4 + r) * 256 + wv * 64 + ct * 16 + L] = pacc[rt][ct][r] + bias;
  }
}

extern "C" void kernel_launch(void* const* d_in, const int* in_sizes, int n_in,
                              void* d_out, int out_size, void* d_ws, size_t ws_size,
                              hipStream_t stream) {
  const float* x      = (const float*)d_in[0];
  const float* w_qkv  = (const float*)d_in[1];
  const float* b_qkv  = (const float*)d_in[2];
  const float* w_proj = (const float*)d_in[3];
  const float* b_proj = (const float*)d_in[4];
  float* out = (float*)d_out;
  short* wbf = (short*)d_ws;                      // 524288 B of bf16 weights

  wconv_kernel<<<256, 256, 0, stream>>>(w_qkv, w_proj, wbf);
  attn_kernel<<<2048, 256, 0, stream>>>(x, wbf, b_qkv, b_proj, out);
}